// Round 1
// baseline (599.609 us; speedup 1.0000x reference)
//
#include <hip/hip_runtime.h>

// Problem: B=32, C=512, c2=256, H=W=32, M=1024.
// Pipeline (all MFMA GEMMs in bf16, fp32 accum):
//   P0: x[b][c][sp] fp32 -> xT[b][sp][c] bf16   (LDS-tiled transpose+convert)
//   W0: Wk/Wv -> Wkv_bf [512][512], Wo -> Wo_bf [512][256]
//   K1: [k;v] = Wkv @ x  -> kT[b][m][c] (k half), vT[b][c][n] (v half, reshape-permuted),
//       s[b][m] = sum_c k (incl. bias)
//   K2: per 64-row tile: gram = kT*kT^T (MFMA), logit=(gram/M - s s^T/M^2)/16,
//       p=exp(logit) (max-free: logits bounded ~0.5), O^T = vT * P^T (P via LDS),
//       normalize by row-sum, write OB[b][m'][c'] (pre-permuted for K3)
//   K3: out = Wo @ O2 + bo + x  (fp32 output)

#define NBATCH 32
#define CIN 512
#define C2 256
#define MM 1024

typedef short bf8 __attribute__((ext_vector_type(8)));
typedef float f32x4 __attribute__((ext_vector_type(4)));

__device__ __forceinline__ short f2bf(float x) {
  unsigned u = __float_as_uint(x);
  u += 0x7fffu + ((u >> 16) & 1u);   // RNE; inputs are finite
  return (short)(u >> 16);
}

#define MFMA16(a, b, c) __builtin_amdgcn_mfma_f32_16x16x32_bf16((a), (b), (c), 0, 0, 0)

// ---------------- P0: transpose + convert x ----------------
__global__ __launch_bounds__(256) void p0_xpose(const float* __restrict__ x,
                                                short* __restrict__ xT) {
  __shared__ float lds[64][65];            // +1 pad: conflict-free transpose
  int cb = blockIdx.x;                     // 0..7   (c tiles of 64)
  int sb = blockIdx.y;                     // 0..15  (sp tiles of 64)
  int b  = blockIdx.z;
  int t  = threadIdx.x;
  int c0 = cb * 64, sp0 = sb * 64;
  const float4* x4 = reinterpret_cast<const float4*>(x);
  #pragma unroll
  for (int j = 0; j < 4; ++j) {
    int lin = t + 256 * j;
    int cl = lin >> 4, s4 = lin & 15;
    float4 v = x4[(((size_t)b * CIN + c0 + cl) * MM + sp0 + s4 * 4) >> 2];
    lds[cl][s4 * 4 + 0] = v.x; lds[cl][s4 * 4 + 1] = v.y;
    lds[cl][s4 * 4 + 2] = v.z; lds[cl][s4 * 4 + 3] = v.w;
  }
  __syncthreads();
  int spl = t >> 2, cs = (t & 3) * 16;
  bf8 o0, o1;
  #pragma unroll
  for (int j = 0; j < 8; ++j) o0[j] = f2bf(lds[cs + j][spl]);
  #pragma unroll
  for (int j = 0; j < 8; ++j) o1[j] = f2bf(lds[cs + 8 + j][spl]);
  size_t base = ((size_t)b * MM + sp0 + spl) * CIN + c0 + cs;
  *reinterpret_cast<bf8*>(xT + base) = o0;
  *reinterpret_cast<bf8*>(xT + base + 8) = o1;
}

// ---------------- W0: weight casts ----------------
__global__ __launch_bounds__(256) void w0_weights(const float* __restrict__ Wk,
                                                  const float* __restrict__ Wv,
                                                  const float* __restrict__ Wo,
                                                  short* __restrict__ Wkv_bf,
                                                  short* __restrict__ Wo_bf) {
  int g = blockIdx.x * 256 + threadIdx.x;
  if (g < 262144) {              // Wkv: rows 0..255 = Wk, 256..511 = Wv
    int o = g >> 9, c = g & 511;
    float v = (o < 256) ? Wk[o * 512 + c] : Wv[(o - 256) * 512 + c];
    Wkv_bf[g] = f2bf(v);
  } else {
    int i2 = g - 262144;         // Wo: 131072 elems
    Wo_bf[i2] = f2bf(Wo[i2]);
  }
}

// ---------------- K1: fused k/v GEMM + row sums ----------------
// Orientation C[row=sp][col=o]; A = xT (16B frags), B = Wkv_bf (16B frags).
__global__ __launch_bounds__(256, 2) void k1_kv(const short* __restrict__ xT,
                                                const short* __restrict__ Wkv,
                                                const float* __restrict__ bk,
                                                const float* __restrict__ bv,
                                                short* __restrict__ kT,
                                                short* __restrict__ vT,
                                                float* __restrict__ s_buf) {
  int t = blockIdx.x, b = blockIdx.y;
  int tid = threadIdx.x;
  int w = tid >> 6, l = tid & 63, q = l >> 4, i = l & 15;
  int sp0 = t * 64;
  int rowA = sp0 + 16 * w + i;                       // A-frag row for this lane
  const short* xrow = xT + ((size_t)b * MM + rowA) * CIN;

  for (int half = 0; half < 2; ++half) {
    f32x4 acc[16];
    f32x4 zz = {0.f, 0.f, 0.f, 0.f};
    #pragma unroll
    for (int ct = 0; ct < 16; ++ct) acc[ct] = zz;
    for (int kq = 0; kq < 16; ++kq) {
      bf8 a = *reinterpret_cast<const bf8*>(xrow + kq * 32 + q * 8);
      #pragma unroll
      for (int ct = 0; ct < 16; ++ct) {
        int o = half * 256 + ct * 16 + i;
        bf8 bb = *reinterpret_cast<const bf8*>(Wkv + o * CIN + kq * 32 + q * 8);
        acc[ct] = MFMA16(a, bb, acc[ct]);
      }
    }
    if (half == 0) {                                  // k half -> kT[m][c] + s
      float prs[4] = {0.f, 0.f, 0.f, 0.f};
      #pragma unroll
      for (int ct = 0; ct < 16; ++ct) {
        float bias = bk[ct * 16 + i];
        #pragma unroll
        for (int r = 0; r < 4; ++r) {
          float val = acc[ct][r] + bias;
          prs[r] += val;
          int sp = sp0 + 16 * w + q * 4 + r;
          kT[((size_t)b * MM + sp) * C2 + ct * 16 + i] = f2bf(val);
        }
      }
      #pragma unroll
      for (int mask = 1; mask <= 8; mask <<= 1) {
        #pragma unroll
        for (int r = 0; r < 4; ++r) prs[r] += __shfl_xor(prs[r], mask, 64);
      }
      if (i == 0) {
        #pragma unroll
        for (int r = 0; r < 4; ++r)
          s_buf[b * MM + sp0 + 16 * w + q * 4 + r] = prs[r];
      }
    } else {                                          // v half -> vT[c][n]
      #pragma unroll
      for (int ct = 0; ct < 16; ++ct) {
        float bias = bv[ct * 16 + i];
        #pragma unroll
        for (int r = 0; r < 4; ++r) {
          float val = acc[ct][r] + bias;
          int sp = sp0 + 16 * w + q * 4 + r;
          int c = sp & 255, h = sp >> 8;              // reshape permutation
          vT[((size_t)b * C2 + c) * MM + 4 * (ct * 16 + i) + h] = f2bf(val);
        }
      }
    }
  }
}

// ---------------- K2: fused gram -> softmax -> PV ----------------
// Wave w owns m = 64*t + 4*i + w (stride-4 set so OB writes are coalesced).
// S GEMM: A-frag & B-frag both from kT (contiguous 16B).
// PV as O^T = vT * P^T: A = vT (global 16B), B = P from per-wave LDS tile.
__global__ __launch_bounds__(256, 2) void k2_attn(const short* __restrict__ kT,
                                                  const short* __restrict__ vT,
                                                  const float* __restrict__ s_buf,
                                                  short* __restrict__ OB) {
  __shared__ __attribute__((aligned(16))) short p_lds[4][16][80];  // pad 80: <=2-way banks
  __shared__ float rs_lds[64];
  int t = blockIdx.x, b = blockIdx.y;
  int tid = threadIdx.x;
  int w = tid >> 6, l = tid & 63, q = l >> 4, i = l & 15;
  const short* kTb = kT + (size_t)b * MM * C2;
  const short* vTb = vT + (size_t)b * C2 * MM;
  const float* sb  = s_buf + b * MM;

  int mi = 64 * t + 4 * i + w;                        // A row (S) / output col (O^T)
  float s_row[4];
  #pragma unroll
  for (int r = 0; r < 4; ++r) s_row[r] = sb[64 * t + 4 * (q * 4 + r) + w];

  f32x4 zz = {0.f, 0.f, 0.f, 0.f};
  f32x4 oacc[16];
  #pragma unroll
  for (int rt = 0; rt < 16; ++rt) oacc[rt] = zz;
  float rowsum[4] = {0.f, 0.f, 0.f, 0.f};

  const float sc1 = 1.0f / 16384.0f;                  // (1/M)*(1/16)
  const float sc2 = 1.0f / 16777216.0f;               // (1/M^2)*(1/16)

  for (int n0 = 0; n0 < MM; n0 += 64) {
    f32x4 sacc[4];
    #pragma unroll
    for (int ct = 0; ct < 4; ++ct) sacc[ct] = zz;
    for (int kq = 0; kq < 8; ++kq) {
      bf8 a = *reinterpret_cast<const bf8*>(kTb + (size_t)mi * C2 + kq * 32 + q * 8);
      #pragma unroll
      for (int ct = 0; ct < 4; ++ct) {
        bf8 bb = *reinterpret_cast<const bf8*>(
            kTb + (size_t)(n0 + ct * 16 + i) * C2 + kq * 32 + q * 8);
        sacc[ct] = MFMA16(a, bb, sacc[ct]);
      }
    }
    // epilogue: logits -> exp -> P (bf16, LDS) + running row sums (max-free, bounded logits)
    #pragma unroll
    for (int ct = 0; ct < 4; ++ct) {
      float s_n = sb[n0 + ct * 16 + i];
      #pragma unroll
      for (int r = 0; r < 4; ++r) {
        float p = __expf(sacc[ct][r] * sc1 - s_row[r] * s_n * sc2);
        rowsum[r] += p;
        p_lds[w][q * 4 + r][ct * 16 + i] = f2bf(p);
      }
    }
    // O^T accumulate: same-wave LDS RAW (compiler inserts lgkmcnt waits)
    #pragma unroll
    for (int kq2 = 0; kq2 < 2; ++kq2) {
      bf8 bp = *reinterpret_cast<const bf8*>(&p_lds[w][i][kq2 * 32 + q * 8]);
      #pragma unroll
      for (int rt = 0; rt < 16; ++rt) {
        bf8 av = *reinterpret_cast<const bf8*>(
            vTb + (size_t)(rt * 16 + i) * MM + n0 + kq2 * 32 + q * 8);
        oacc[rt] = MFMA16(av, bp, oacc[rt]);
      }
    }
  }
  #pragma unroll
  for (int mask = 1; mask <= 8; mask <<= 1) {
    #pragma unroll
    for (int r = 0; r < 4; ++r) rowsum[r] += __shfl_xor(rowsum[r], mask, 64);
  }
  if (i == 0) {
    #pragma unroll
    for (int r = 0; r < 4; ++r) rs_lds[w * 16 + q * 4 + r] = rowsum[r];
  }
  float rinv = 1.0f / rs_lds[w * 16 + i];             // same-wave LDS, auto waitcnt
  short* obb = OB + (size_t)b * MM * C2;
  #pragma unroll
  for (int rt = 0; rt < 16; ++rt) {
    #pragma unroll
    for (int r = 0; r < 4; ++r) {
      int c = rt * 16 + q * 4 + r;
      // O[m][c] -> OB[(m&3)*256 + c][m>>2]; m&3==w, m>>2==16t+i -> coalesced over i
      obb[(w * 256 + c) * C2 + 16 * t + i] = f2bf(oacc[rt][r] * rinv);
    }
  }
}

// ---------------- K3: output projection + bias + residual ----------------
// C[row=O][col=sp]; A = Wo_bf (16B frags), B = OB (16B frags, pre-permuted).
__global__ __launch_bounds__(256) void k3_out(const short* __restrict__ Wo_bf,
                                              const short* __restrict__ OB,
                                              const float* __restrict__ bo,
                                              const float* __restrict__ x,
                                              float* __restrict__ out) {
  int st = blockIdx.x;       // sp tile (64)
  int ot = blockIdx.y;       // O tile (128)
  int b  = blockIdx.z;
  int tid = threadIdx.x;
  int w = tid >> 6, l = tid & 63, q = l >> 4, i = l & 15;
  const short* obb = OB + (size_t)b * MM * C2;
  f32x4 zz = {0.f, 0.f, 0.f, 0.f};
  f32x4 acc[2][4];
  #pragma unroll
  for (int rt = 0; rt < 2; ++rt)
    #pragma unroll
    for (int ct = 0; ct < 4; ++ct) acc[rt][ct] = zz;
  for (int kq = 0; kq < 8; ++kq) {
    bf8 a0 = *reinterpret_cast<const bf8*>(
        Wo_bf + (ot * 128 + w * 32 + i) * C2 + kq * 32 + q * 8);
    bf8 a1 = *reinterpret_cast<const bf8*>(
        Wo_bf + (ot * 128 + w * 32 + 16 + i) * C2 + kq * 32 + q * 8);
    #pragma unroll
    for (int ct = 0; ct < 4; ++ct) {
      bf8 bb = *reinterpret_cast<const bf8*>(
          obb + (st * 64 + ct * 16 + i) * C2 + kq * 32 + q * 8);
      acc[0][ct] = MFMA16(a0, bb, acc[0][ct]);
      acc[1][ct] = MFMA16(a1, bb, acc[1][ct]);
    }
  }
  #pragma unroll
  for (int rt = 0; rt < 2; ++rt) {
    #pragma unroll
    for (int r = 0; r < 4; ++r) {
      int orow = ot * 128 + w * 32 + rt * 16 + q * 4 + r;
      float bias = bo[orow];
      #pragma unroll
      for (int ct = 0; ct < 4; ++ct) {
        int sp = st * 64 + ct * 16 + i;
        size_t idx = ((size_t)b * CIN + orow) * MM + sp;
        out[idx] = acc[rt][ct][r] + bias + x[idx];
      }
    }
  }
}

extern "C" void kernel_launch(void* const* d_in, const int* in_sizes, int n_in,
                              void* d_out, int out_size, void* d_ws, size_t ws_size,
                              hipStream_t stream) {
  (void)in_sizes; (void)n_in; (void)out_size; (void)ws_size;
  const float* x  = (const float*)d_in[0];
  const float* Wk = (const float*)d_in[1];
  const float* bk = (const float*)d_in[2];
  const float* Wv = (const float*)d_in[3];
  const float* bv = (const float*)d_in[4];
  const float* Wo = (const float*)d_in[5];
  const float* bo = (const float*)d_in[6];
  float* out = (float*)d_out;
  char* ws = (char*)d_ws;

  // ws layout (bytes). OB aliases xT: xT is dead after K1, OB written in K2. ~64.9 MB total.
  short* xT     = (short*)(ws);                  // 32 MB  [0, 33554432)
  short* OB     = (short*)(ws);                  // 16 MB  (alias, used after K1)
  short* kTb    = (short*)(ws + 33554432);       // 16 MB
  short* vTb    = (short*)(ws + 50331648);       // 16 MB
  short* Wkv_bf = (short*)(ws + 67108864);       // 512 KB
  short* Wo_bf  = (short*)(ws + 67633152);       // 256 KB
  float* s_buf  = (float*)(ws + 67895296);       // 128 KB

  p0_xpose<<<dim3(8, 16, 32), 256, 0, stream>>>(x, xT);
  w0_weights<<<1536, 256, 0, stream>>>(Wk, Wv, Wo, Wkv_bf, Wo_bf);
  k1_kv<<<dim3(16, 32), 256, 0, stream>>>(xT, Wkv_bf, bk, bv, kTb, vTb, s_buf);
  k2_attn<<<dim3(16, 32), 256, 0, stream>>>(kTb, vTb, s_buf, OB);
  k3_out<<<dim3(16, 4, 32), 256, 0, stream>>>(Wo_bf, OB, bo, x, out);
}

// Round 2
// 262.750 us; speedup vs baseline: 2.2820x; 2.2820x over previous
//
#include <hip/hip_runtime.h>

// B=32, C=512, c2=256, M=1024. All GEMMs bf16 MFMA (fp32 accum), m97-style:
// 128x128 tile, BK=64, global_load_lds(16B) staging, XOR-swizzled chunks,
// 4 waves * (4x4 of 16x16x32) accumulators.
//
// P0 : x[b][c][sp] fp32 -> xT[b*1024+sp][c] bf16
// W0 : weight casts (Wkv = [Wk;Wv] 512x512, Wo 512x256)
// K1 : [32768x512]x[512x512]: k-half -> kT[m][c] + row-sum partials,
//      v-half -> vT[b][c][n] (reshape-permuted)
// K1b: combine 4 row-sum partials -> s_buf
// K2a: gram = kT*kT^T per batch (1024x1024, K=256), logits -> exp -> P bf16
//      (LDS-restaged 128B stores) + rowsum partials
// K2c: rowsum partials -> 1/rowsum
// K2b: O = P * vT_B^T (K=1024), normalize, write OB[(m&3)*256+c][m>>2]
// K3 : out = Wo @ O2 + bo + x (fp32), B = OB (k-major)

typedef short bf8 __attribute__((ext_vector_type(8)));
typedef float f32x4 __attribute__((ext_vector_type(4)));

#define MFMA16(a, b, c) __builtin_amdgcn_mfma_f32_16x16x32_bf16((a), (b), (c), 0, 0, 0)

__device__ __forceinline__ short f2bf(float x) {
  unsigned u = __float_as_uint(x);
  u += 0x7fffu + ((u >> 16) & 1u);   // RNE, finite inputs
  return (short)(u >> 16);
}

__device__ __forceinline__ void gll16(const short* g, void* l) {
  __builtin_amdgcn_global_load_lds(
      (const __attribute__((address_space(1))) unsigned int*)g,
      (__attribute__((address_space(3))) unsigned int*)l, 16, 0, 0);
}

// ---- shared GEMM core: C[128][128] tile, A/B k-major bf16, K = ksteps*64 ----
__device__ __forceinline__ void gemm_core(const short* __restrict__ A,
                                          const short* __restrict__ B,
                                          int ldA, int ldB, int ksteps,
                                          char* smem, f32x4 acc[4][4]) {
  const int tid = threadIdx.x;
  const int w = tid >> 6, l = tid & 63;
  const int q = l >> 4, i = l & 15;
  const int wm = w & 1, wn = w >> 1;
  const int srow = l >> 3;
  const int gcol = ((l & 7) ^ srow) * 8;        // swizzled 16B chunk (shorts)
  f32x4 zz = {0.f, 0.f, 0.f, 0.f};
  #pragma unroll
  for (int mt = 0; mt < 4; ++mt)
    #pragma unroll
    for (int nt = 0; nt < 4; ++nt) acc[mt][nt] = zz;

  for (int ks = 0; ks < ksteps; ++ks) {
    __syncthreads();                            // LDS free (prev reads done)
    const short* Ak = A + ks * 64 + gcol;
    const short* Bk = B + ks * 64 + gcol;
    #pragma unroll
    for (int j = 0; j < 4; ++j) {
      int s = w * 4 + j;
      size_t row = (size_t)(s * 8 + srow);
      gll16(Ak + row * ldA, smem + s * 1024);
      gll16(Bk + row * ldB, smem + 16384 + s * 1024);
    }
    __syncthreads();                            // staged data visible
    #pragma unroll
    for (int kq = 0; kq < 2; ++kq) {
      int sw = ((kq * 4 + q) ^ (i & 7)) * 16;   // swizzled read offset (bytes)
      bf8 af[4], bq[4];
      #pragma unroll
      for (int mt = 0; mt < 4; ++mt)
        af[mt] = *(const bf8*)(smem + (wm * 64 + mt * 16 + i) * 128 + sw);
      #pragma unroll
      for (int nt = 0; nt < 4; ++nt)
        bq[nt] = *(const bf8*)(smem + 16384 + (wn * 64 + nt * 16 + i) * 128 + sw);
      #pragma unroll
      for (int mt = 0; mt < 4; ++mt)
        #pragma unroll
        for (int nt = 0; nt < 4; ++nt)
          acc[mt][nt] = MFMA16(af[mt], bq[nt], acc[mt][nt]);
    }
  }
}

// ---------------- P0: transpose + convert x ----------------
__global__ __launch_bounds__(256) void p0_xpose(const float* __restrict__ x,
                                                short* __restrict__ xT) {
  __shared__ float lds[64][65];
  int cb = blockIdx.x, sb = blockIdx.y, b = blockIdx.z;
  int t = threadIdx.x;
  int c0 = cb * 64, sp0 = sb * 64;
  const float4* x4 = reinterpret_cast<const float4*>(x);
  #pragma unroll
  for (int j = 0; j < 4; ++j) {
    int lin = t + 256 * j;
    int cl = lin >> 4, s4 = lin & 15;
    float4 v = x4[(((size_t)b * 512 + c0 + cl) * 1024 + sp0 + s4 * 4) >> 2];
    lds[cl][s4 * 4 + 0] = v.x; lds[cl][s4 * 4 + 1] = v.y;
    lds[cl][s4 * 4 + 2] = v.z; lds[cl][s4 * 4 + 3] = v.w;
  }
  __syncthreads();
  int spl = t >> 2, cs = (t & 3) * 16;
  bf8 o0, o1;
  #pragma unroll
  for (int j = 0; j < 8; ++j) o0[j] = f2bf(lds[cs + j][spl]);
  #pragma unroll
  for (int j = 0; j < 8; ++j) o1[j] = f2bf(lds[cs + 8 + j][spl]);
  size_t base = ((size_t)b * 1024 + sp0 + spl) * 512 + c0 + cs;
  *reinterpret_cast<bf8*>(xT + base) = o0;
  *reinterpret_cast<bf8*>(xT + base + 8) = o1;
}

// ---------------- W0: weight casts ----------------
__global__ __launch_bounds__(256) void w0_weights(const float* __restrict__ Wk,
                                                  const float* __restrict__ Wv,
                                                  const float* __restrict__ Wo,
                                                  short* __restrict__ Wkv_bf,
                                                  short* __restrict__ Wo_bf) {
  int g = blockIdx.x * 256 + threadIdx.x;
  if (g < 262144) {
    int o = g >> 9, c = g & 511;
    float v = (o < 256) ? Wk[o * 512 + c] : Wv[(o - 256) * 512 + c];
    Wkv_bf[g] = f2bf(v);
  } else {
    int i2 = g - 262144;
    Wo_bf[i2] = f2bf(Wo[i2]);
  }
}

// ---------------- K1: fused k/v projection GEMM ----------------
__global__ __launch_bounds__(256, 2) void k1_kv(const short* __restrict__ xT,
                                                const short* __restrict__ Wkv,
                                                const float* __restrict__ bk,
                                                const float* __restrict__ bv,
                                                short* __restrict__ kT,
                                                short* __restrict__ vT,
                                                float* __restrict__ s_part) {
  __shared__ __attribute__((aligned(16))) char smem[32768];
  f32x4 acc[4][4];
  int bm = blockIdx.x, bn = blockIdx.y;
  gemm_core(xT + (size_t)bm * 128 * 512, Wkv + (size_t)bn * 128 * 512,
            512, 512, 8, smem, acc);
  int tid = threadIdx.x;
  int w = tid >> 6, l = tid & 63, q = l >> 4, i = l & 15;
  int wm = w & 1, wn = w >> 1;
  int mbase = bm * 128 + wm * 64;
  int nbase = bn * 128 + wn * 64;
  if (bn < 2) {                                  // k half
    float rp[4][4];
    #pragma unroll
    for (int mt = 0; mt < 4; ++mt)
      #pragma unroll
      for (int r = 0; r < 4; ++r) rp[mt][r] = 0.f;
    #pragma unroll
    for (int mt = 0; mt < 4; ++mt)
      #pragma unroll
      for (int nt = 0; nt < 4; ++nt) {
        float bias = bk[nbase + nt * 16 + i];
        #pragma unroll
        for (int r = 0; r < 4; ++r) {
          float val = acc[mt][nt][r] + bias;
          int mg = mbase + mt * 16 + q * 4 + r;
          kT[(size_t)mg * 256 + nbase + nt * 16 + i] = f2bf(val);
          rp[mt][r] += val;
        }
      }
    #pragma unroll
    for (int mask = 1; mask <= 8; mask <<= 1)
      #pragma unroll
      for (int mt = 0; mt < 4; ++mt)
        #pragma unroll
        for (int r = 0; r < 4; ++r) rp[mt][r] += __shfl_xor(rp[mt][r], mask, 64);
    if (i == 0) {
      int pg = bn * 2 + wn;
      #pragma unroll
      for (int mt = 0; mt < 4; ++mt)
        #pragma unroll
        for (int r = 0; r < 4; ++r)
          s_part[pg * 32768 + mbase + mt * 16 + q * 4 + r] = rp[mt][r];
    }
  } else {                                       // v half -> vT permuted
    #pragma unroll
    for (int mt = 0; mt < 4; ++mt)
      #pragma unroll
      for (int nt = 0; nt < 4; ++nt) {
        int o2 = nbase + nt * 16 + i - 256;
        float bias = bv[o2];
        #pragma unroll
        for (int r = 0; r < 4; ++r) {
          float val = acc[mt][nt][r] + bias;
          int mg = mbase + mt * 16 + q * 4 + r;
          int b = mg >> 10, sp = mg & 1023;
          vT[((size_t)b * 256 + (sp & 255)) * 1024 + 4 * o2 + (sp >> 8)] = f2bf(val);
        }
      }
  }
}

__global__ __launch_bounds__(256) void k1b_sum(const float* __restrict__ s_part,
                                               float* __restrict__ s_buf) {
  int t = blockIdx.x * 256 + threadIdx.x;
  s_buf[t] = s_part[t] + s_part[32768 + t] + s_part[65536 + t] + s_part[98304 + t];
}

// ---------------- K2a: gram -> exp -> P ----------------
__global__ __launch_bounds__(256, 2) void k2a_gram(const short* __restrict__ kT,
                                                   const float* __restrict__ s_buf,
                                                   short* __restrict__ P,
                                                   float* __restrict__ rsum_part) {
  __shared__ __attribute__((aligned(16))) char smem[36864];
  f32x4 acc[4][4];
  int bm = blockIdx.x, bn = blockIdx.y, b = blockIdx.z;
  const short* kb = kT + (size_t)b * 1024 * 256;
  gemm_core(kb + (size_t)bm * 128 * 256, kb + (size_t)bn * 128 * 256,
            256, 256, 4, smem, acc);
  int tid = threadIdx.x;
  int w = tid >> 6, l = tid & 63, q = l >> 4, i = l & 15;
  int wm = w & 1, wn = w >> 1;
  int mloc = bm * 128 + wm * 64, nloc = bn * 128 + wn * 64;
  const float sc1 = 1.0f / 16384.0f;             // (1/M)/16
  const float sc2 = 1.0f / 16777216.0f;          // (1/M^2)/16
  const float* sB = s_buf + b * 1024;
  float sm[4][4], sn[4];
  #pragma unroll
  for (int mt = 0; mt < 4; ++mt)
    #pragma unroll
    for (int r = 0; r < 4; ++r) sm[mt][r] = sB[mloc + mt * 16 + q * 4 + r];
  #pragma unroll
  for (int nt = 0; nt < 4; ++nt) sn[nt] = sB[nloc + nt * 16 + i];

  __syncthreads();                               // frag reads done; reuse smem
  short* pb = (short*)(smem + w * 9216);         // 64 rows x 72 shorts (144 B)
  float rp[4][4];
  #pragma unroll
  for (int mt = 0; mt < 4; ++mt)
    #pragma unroll
    for (int r = 0; r < 4; ++r) rp[mt][r] = 0.f;
  #pragma unroll
  for (int mt = 0; mt < 4; ++mt)
    #pragma unroll
    for (int nt = 0; nt < 4; ++nt)
      #pragma unroll
      for (int r = 0; r < 4; ++r) {
        float p = __expf(acc[mt][nt][r] * sc1 - sm[mt][r] * sn[nt] * sc2);
        rp[mt][r] += p;
        pb[(mt * 16 + q * 4 + r) * 72 + nt * 16 + i] = f2bf(p);
      }
  #pragma unroll
  for (int mask = 1; mask <= 8; mask <<= 1)
    #pragma unroll
    for (int mt = 0; mt < 4; ++mt)
      #pragma unroll
      for (int r = 0; r < 4; ++r) rp[mt][r] += __shfl_xor(rp[mt][r], mask, 64);
  if (i == 0) {
    int pg = bn * 2 + wn;
    float* rpp = rsum_part + pg * 32768 + b * 1024;
    #pragma unroll
    for (int mt = 0; mt < 4; ++mt)
      #pragma unroll
      for (int r = 0; r < 4; ++r)
        rpp[mloc + mt * 16 + q * 4 + r] = rp[mt][r];
  }
  // coalesced 128B-row store of the wave's 64x64 P tile (same-wave LDS RAW)
  short* Pb = P + ((size_t)b * 1024 + mloc) * 1024 + nloc;
  #pragma unroll
  for (int j = 0; j < 8; ++j) {
    int row = j * 8 + (l >> 3), c = l & 7;
    bf8 vv = *(const bf8*)(pb + row * 72 + c * 8);
    *(bf8*)(Pb + (size_t)row * 1024 + c * 8) = vv;
  }
}

__global__ __launch_bounds__(256) void k2c_rinv(const float* __restrict__ rsum_part,
                                                float* __restrict__ rinv) {
  int t = blockIdx.x * 256 + threadIdx.x;
  float s = 0.f;
  #pragma unroll
  for (int pg = 0; pg < 16; ++pg) s += rsum_part[pg * 32768 + t];
  rinv[t] = 1.0f / s;
}

// ---------------- K2b: O = P * v, normalize, write OB ----------------
__global__ __launch_bounds__(256, 2) void k2b_pv(const short* __restrict__ P,
                                                 const short* __restrict__ vT,
                                                 const float* __restrict__ rinv,
                                                 short* __restrict__ OB) {
  __shared__ __attribute__((aligned(16))) char smem[32768];
  f32x4 acc[4][4];
  int bm = blockIdx.x, bn = blockIdx.y, b = blockIdx.z;
  gemm_core(P + ((size_t)b * 1024 + bm * 128) * 1024,
            vT + ((size_t)b * 256 + bn * 128) * 1024, 1024, 1024, 16, smem, acc);
  int tid = threadIdx.x;
  int w = tid >> 6, l = tid & 63, q = l >> 4, i = l & 15;
  int wm = w & 1, wn = w >> 1;
  int mloc = bm * 128 + wm * 64, cloc = bn * 128 + wn * 64;
  float ri[4][4];
  #pragma unroll
  for (int mt = 0; mt < 4; ++mt)
    #pragma unroll
    for (int r = 0; r < 4; ++r)
      ri[mt][r] = rinv[b * 1024 + mloc + mt * 16 + q * 4 + r];
  __syncthreads();                               // reuse smem per-wave
  short* ob = (short*)(smem + w * 8192);         // 256 rows x 16 shorts
  #pragma unroll
  for (int mt = 0; mt < 4; ++mt)
    #pragma unroll
    for (int nt = 0; nt < 4; ++nt)
      #pragma unroll
      for (int r = 0; r < 4; ++r) {
        int lr = r * 64 + nt * 16 + i;           // r == m&3 here
        ob[lr * 16 + mt * 4 + q] = f2bf(acc[mt][nt][r] * ri[mt][r]);
      }
  short* obg = OB + (size_t)b * 1024 * 256;
  int colbase = mloc >> 2;
  #pragma unroll
  for (int j = 0; j < 8; ++j) {
    int lr = j * 32 + (l >> 1), ch = l & 1;
    bf8 vv = *(const bf8*)(ob + lr * 16 + ch * 8);
    int rr = lr >> 6, cc = lr & 63;
    *(bf8*)(obg + ((size_t)rr * 256 + cloc + cc) * 256 + colbase + ch * 8) = vv;
  }
}

// ---------------- K3: output projection + bias + residual ----------------
__global__ __launch_bounds__(256, 2) void k3_out(const short* __restrict__ Wo_bf,
                                                 const short* __restrict__ OB,
                                                 const float* __restrict__ bo,
                                                 const float* __restrict__ x,
                                                 float* __restrict__ out) {
  __shared__ __attribute__((aligned(16))) char smem[32768];
  f32x4 acc[4][4];
  int bm = blockIdx.x, bn = blockIdx.y, b = blockIdx.z;
  gemm_core(Wo_bf + (size_t)bm * 128 * 256,
            OB + ((size_t)b * 1024 + bn * 128) * 256, 256, 256, 4, smem, acc);
  int tid = threadIdx.x;
  int w = tid >> 6, l = tid & 63, q = l >> 4, i = l & 15;
  int wm = w & 1, wn = w >> 1;
  int oloc = bm * 128 + wm * 64, sploc = bn * 128 + wn * 64;
  #pragma unroll
  for (int mt = 0; mt < 4; ++mt)
    #pragma unroll
    for (int r = 0; r < 4; ++r) {
      int o = oloc + mt * 16 + q * 4 + r;
      float bias = bo[o];
      #pragma unroll
      for (int nt = 0; nt < 4; ++nt) {
        int sp = sploc + nt * 16 + i;
        size_t idx = ((size_t)b * 512 + o) * 1024 + sp;
        out[idx] = acc[mt][nt][r] + bias + x[idx];
      }
    }
}

extern "C" void kernel_launch(void* const* d_in, const int* in_sizes, int n_in,
                              void* d_out, int out_size, void* d_ws, size_t ws_size,
                              hipStream_t stream) {
  (void)in_sizes; (void)n_in; (void)out_size; (void)ws_size;
  const float* x  = (const float*)d_in[0];
  const float* Wk = (const float*)d_in[1];
  const float* bk = (const float*)d_in[2];
  const float* Wv = (const float*)d_in[3];
  const float* bv = (const float*)d_in[4];
  const float* Wo = (const float*)d_in[5];
  const float* bo = (const float*)d_in[6];
  float* out = (float*)d_out;
  char* ws = (char*)d_ws;

  // ws layout (~99.5 MB), time-aliased:
  //   [0,64M)   : xT (P0->K1, 32 MB) then P (K2a->K2b, 64 MB)
  //   [64M,80M) : kT (K1->K2a) then OB (K2b->K3)
  //   [80M,96M) : vT (K1->K2b)
  //   [96M,...) : weights + reduction buffers
  short* xT     = (short*)(ws);
  short* Pbuf   = (short*)(ws);
  short* kTb    = (short*)(ws + 67108864);
  short* OB     = (short*)(ws + 67108864);
  short* vTb    = (short*)(ws + 83886080);
  short* Wkv_bf = (short*)(ws + 100663296);
  short* Wo_bf  = (short*)(ws + 101187584);
  float* s_part = (float*)(ws + 101449728);
  float* s_buf  = (float*)(ws + 101974016);
  float* rsum_p = (float*)(ws + 102105088);
  float* rinv   = (float*)(ws + 104202240);

  p0_xpose<<<dim3(8, 16, 32), 256, 0, stream>>>(x, xT);
  w0_weights<<<1536, 256, 0, stream>>>(Wk, Wv, Wo, Wkv_bf, Wo_bf);
  k1_kv<<<dim3(256, 4), 256, 0, stream>>>(xT, Wkv_bf, bk, bv, kTb, vTb, s_part);
  k1b_sum<<<128, 256, 0, stream>>>(s_part, s_buf);
  k2a_gram<<<dim3(8, 8, 32), 256, 0, stream>>>(kTb, s_buf, Pbuf, rsum_p);
  k2c_rinv<<<128, 256, 0, stream>>>(rsum_p, rinv);
  k2b_pv<<<dim3(8, 2, 32), 256, 0, stream>>>(Pbuf, vTb, rinv, OB);
  k3_out<<<dim3(4, 8, 32), 256, 0, stream>>>(Wo_bf, OB, bo, x, out);
}

// Round 3
// 252.159 us; speedup vs baseline: 2.3779x; 1.0420x over previous
//
#include <hip/hip_runtime.h>

// B=32, C=512, c2=256, M=1024. All GEMMs bf16 MFMA (fp32 accum), m97-style:
// 128x128 (or fused) tiles, BK=64, global_load_lds(16B) staging, XOR-swizzled
// chunks.
//
// P0 : x[b][c][sp] fp32 -> xT[b*1024+sp][c] bf16
// W0 : weight casts (Wkv = [Wk;Wv] 512x512, Wo 512x256)
// K1 : [32768x512]x[512x512]: k-half -> kT[m][c] + row-sum partials,
//      v-half -> vT[b][c][n] (reshape-permuted)
// K1b: combine 4 row-sum partials -> s_buf
// K2 : FUSED flash-style attention per (64-row m-stripe, batch):
//      A(kT stripe) resident in LDS; per 128-n chunk: S GEMM -> exp -> P in
//      LDS (A-operand layout) -> PV GEMM; then rowsum reduce + normalize +
//      OB[(m&3)*256+c][m>>2] write (LDS-restaged)
// K3 : out = Wo @ O2 + bo + x (fp32), B = OB (k-major)

typedef short bf8 __attribute__((ext_vector_type(8)));
typedef float f32x4 __attribute__((ext_vector_type(4)));

#define MFMA16(a, b, c) __builtin_amdgcn_mfma_f32_16x16x32_bf16((a), (b), (c), 0, 0, 0)

__device__ __forceinline__ short f2bf(float x) {
  unsigned u = __float_as_uint(x);
  u += 0x7fffu + ((u >> 16) & 1u);   // RNE, finite inputs
  return (short)(u >> 16);
}

__device__ __forceinline__ void gll16(const short* g, void* l) {
  __builtin_amdgcn_global_load_lds(
      (const __attribute__((address_space(1))) unsigned int*)g,
      (__attribute__((address_space(3))) unsigned int*)l, 16, 0, 0);
}

// ---- shared GEMM core: C[128][128] tile, A/B k-major bf16, K = ksteps*64 ----
__device__ __forceinline__ void gemm_core(const short* __restrict__ A,
                                          const short* __restrict__ B,
                                          int ldA, int ldB, int ksteps,
                                          char* smem, f32x4 acc[4][4]) {
  const int tid = threadIdx.x;
  const int w = tid >> 6, l = tid & 63;
  const int q = l >> 4, i = l & 15;
  const int wm = w & 1, wn = w >> 1;
  const int srow = l >> 3;
  const int gcol = ((l & 7) ^ srow) * 8;        // swizzled 16B chunk (shorts)
  f32x4 zz = {0.f, 0.f, 0.f, 0.f};
  #pragma unroll
  for (int mt = 0; mt < 4; ++mt)
    #pragma unroll
    for (int nt = 0; nt < 4; ++nt) acc[mt][nt] = zz;

  for (int ks = 0; ks < ksteps; ++ks) {
    __syncthreads();                            // LDS free (prev reads done)
    const short* Ak = A + ks * 64 + gcol;
    const short* Bk = B + ks * 64 + gcol;
    #pragma unroll
    for (int j = 0; j < 4; ++j) {
      int s = w * 4 + j;
      size_t row = (size_t)(s * 8 + srow);
      gll16(Ak + row * ldA, smem + s * 1024);
      gll16(Bk + row * ldB, smem + 16384 + s * 1024);
    }
    __syncthreads();                            // staged data visible
    #pragma unroll
    for (int kq = 0; kq < 2; ++kq) {
      int sw = ((kq * 4 + q) ^ (i & 7)) * 16;   // swizzled read offset (bytes)
      bf8 af[4], bq[4];
      #pragma unroll
      for (int mt = 0; mt < 4; ++mt)
        af[mt] = *(const bf8*)(smem + (wm * 64 + mt * 16 + i) * 128 + sw);
      #pragma unroll
      for (int nt = 0; nt < 4; ++nt)
        bq[nt] = *(const bf8*)(smem + 16384 + (wn * 64 + nt * 16 + i) * 128 + sw);
      #pragma unroll
      for (int mt = 0; mt < 4; ++mt)
        #pragma unroll
        for (int nt = 0; nt < 4; ++nt)
          acc[mt][nt] = MFMA16(af[mt], bq[nt], acc[mt][nt]);
    }
  }
}

// ---------------- P0: transpose + convert x ----------------
__global__ __launch_bounds__(256) void p0_xpose(const float* __restrict__ x,
                                                short* __restrict__ xT) {
  __shared__ float lds[64][65];
  int cb = blockIdx.x, sb = blockIdx.y, b = blockIdx.z;
  int t = threadIdx.x;
  int c0 = cb * 64, sp0 = sb * 64;
  const float4* x4 = reinterpret_cast<const float4*>(x);
  #pragma unroll
  for (int j = 0; j < 4; ++j) {
    int lin = t + 256 * j;
    int cl = lin >> 4, s4 = lin & 15;
    float4 v = x4[(((size_t)b * 512 + c0 + cl) * 1024 + sp0 + s4 * 4) >> 2];
    lds[cl][s4 * 4 + 0] = v.x; lds[cl][s4 * 4 + 1] = v.y;
    lds[cl][s4 * 4 + 2] = v.z; lds[cl][s4 * 4 + 3] = v.w;
  }
  __syncthreads();
  int spl = t >> 2, cs = (t & 3) * 16;
  bf8 o0, o1;
  #pragma unroll
  for (int j = 0; j < 8; ++j) o0[j] = f2bf(lds[cs + j][spl]);
  #pragma unroll
  for (int j = 0; j < 8; ++j) o1[j] = f2bf(lds[cs + 8 + j][spl]);
  size_t base = ((size_t)b * 1024 + sp0 + spl) * 512 + c0 + cs;
  *reinterpret_cast<bf8*>(xT + base) = o0;
  *reinterpret_cast<bf8*>(xT + base + 8) = o1;
}

// ---------------- W0: weight casts ----------------
__global__ __launch_bounds__(256) void w0_weights(const float* __restrict__ Wk,
                                                  const float* __restrict__ Wv,
                                                  const float* __restrict__ Wo,
                                                  short* __restrict__ Wkv_bf,
                                                  short* __restrict__ Wo_bf) {
  int g = blockIdx.x * 256 + threadIdx.x;
  if (g < 262144) {
    int o = g >> 9, c = g & 511;
    float v = (o < 256) ? Wk[o * 512 + c] : Wv[(o - 256) * 512 + c];
    Wkv_bf[g] = f2bf(v);
  } else {
    int i2 = g - 262144;
    Wo_bf[i2] = f2bf(Wo[i2]);
  }
}

// ---------------- K1: fused k/v projection GEMM ----------------
__global__ __launch_bounds__(256, 2) void k1_kv(const short* __restrict__ xT,
                                                const short* __restrict__ Wkv,
                                                const float* __restrict__ bk,
                                                const float* __restrict__ bv,
                                                short* __restrict__ kT,
                                                short* __restrict__ vT,
                                                float* __restrict__ s_part) {
  __shared__ __attribute__((aligned(16))) char smem[32768];
  f32x4 acc[4][4];
  int bm = blockIdx.x, bn = blockIdx.y;
  gemm_core(xT + (size_t)bm * 128 * 512, Wkv + (size_t)bn * 128 * 512,
            512, 512, 8, smem, acc);
  int tid = threadIdx.x;
  int w = tid >> 6, l = tid & 63, q = l >> 4, i = l & 15;
  int wm = w & 1, wn = w >> 1;
  int mbase = bm * 128 + wm * 64;
  int nbase = bn * 128 + wn * 64;
  if (bn < 2) {                                  // k half
    float rp[4][4];
    #pragma unroll
    for (int mt = 0; mt < 4; ++mt)
      #pragma unroll
      for (int r = 0; r < 4; ++r) rp[mt][r] = 0.f;
    #pragma unroll
    for (int mt = 0; mt < 4; ++mt)
      #pragma unroll
      for (int nt = 0; nt < 4; ++nt) {
        float bias = bk[nbase + nt * 16 + i];
        #pragma unroll
        for (int r = 0; r < 4; ++r) {
          float val = acc[mt][nt][r] + bias;
          int mg = mbase + mt * 16 + q * 4 + r;
          kT[(size_t)mg * 256 + nbase + nt * 16 + i] = f2bf(val);
          rp[mt][r] += val;
        }
      }
    #pragma unroll
    for (int mask = 1; mask <= 8; mask <<= 1)
      #pragma unroll
      for (int mt = 0; mt < 4; ++mt)
        #pragma unroll
        for (int r = 0; r < 4; ++r) rp[mt][r] += __shfl_xor(rp[mt][r], mask, 64);
    if (i == 0) {
      int pg = bn * 2 + wn;
      #pragma unroll
      for (int mt = 0; mt < 4; ++mt)
        #pragma unroll
        for (int r = 0; r < 4; ++r)
          s_part[pg * 32768 + mbase + mt * 16 + q * 4 + r] = rp[mt][r];
    }
  } else {                                       // v half -> vT permuted
    #pragma unroll
    for (int mt = 0; mt < 4; ++mt)
      #pragma unroll
      for (int nt = 0; nt < 4; ++nt) {
        int o2 = nbase + nt * 16 + i - 256;
        float bias = bv[o2];
        #pragma unroll
        for (int r = 0; r < 4; ++r) {
          float val = acc[mt][nt][r] + bias;
          int mg = mbase + mt * 16 + q * 4 + r;
          int b = mg >> 10, sp = mg & 1023;
          vT[((size_t)b * 256 + (sp & 255)) * 1024 + 4 * o2 + (sp >> 8)] = f2bf(val);
        }
      }
  }
}

__global__ __launch_bounds__(256) void k1b_sum(const float* __restrict__ s_part,
                                               float* __restrict__ s_buf) {
  int t = blockIdx.x * 256 + threadIdx.x;
  s_buf[t] = s_part[t] + s_part[32768 + t] + s_part[65536 + t] + s_part[98304 + t];
}

// ---------------- K2: fused gram -> softmax -> PV -> OB ----------------
// Block = (64-row m-stripe bm, batch b). LDS: A panels 32K | P panels 16K |
// Bst 32K staging (wave-self-contained slots). 2 blocks/CU.
__global__ __launch_bounds__(256, 2) void k2_fused(const short* __restrict__ kT,
                                                   const short* __restrict__ vT,
                                                   const float* __restrict__ s_buf,
                                                   short* __restrict__ OB) {
  __shared__ __attribute__((aligned(16))) char smem[81920];
  char* Apan = smem;            // 4 panels x (64 rows x 128 B)
  char* Ppan = smem + 32768;    // 2 panels x (64 rows x 128 B)
  char* Bst  = smem + 49152;    // 32 KB staging

  const int bm = blockIdx.x, b = blockIdx.y;
  const int tid = threadIdx.x;
  const int w = tid >> 6, l = tid & 63;
  const int q = l >> 4, i = l & 15;
  const int srow = l >> 3;
  const int gcol = ((l & 7) ^ srow) * 8;

  const short* kTb = kT + (size_t)b * 1024 * 256;
  const short* vTb = vT + (size_t)b * 256 * 1024;
  const float* sB = s_buf + b * 1024;

  // stage resident A (kT m-stripe 64x256) into 4 swizzled panels
  {
    const short* Am = kTb + (size_t)bm * 64 * 256;
    #pragma unroll
    for (int ks = 0; ks < 4; ++ks)
      #pragma unroll
      for (int j2 = 0; j2 < 2; ++j2) {
        int s2 = w * 2 + j2;
        gll16(Am + (size_t)(s2 * 8 + srow) * 256 + ks * 64 + gcol,
              Apan + ks * 8192 + s2 * 1024);
      }
  }

  float sm[4][4];
  #pragma unroll
  for (int mt = 0; mt < 4; ++mt)
    #pragma unroll
    for (int r = 0; r < 4; ++r) sm[mt][r] = sB[bm * 64 + mt * 16 + q * 4 + r];

  f32x4 zz = {0.f, 0.f, 0.f, 0.f};
  f32x4 acc_o[4][4];
  #pragma unroll
  for (int mt = 0; mt < 4; ++mt)
    #pragma unroll
    for (int ct = 0; ct < 4; ++ct) acc_o[mt][ct] = zz;
  float rowsum[4][4];
  #pragma unroll
  for (int mt = 0; mt < 4; ++mt)
    #pragma unroll
    for (int r = 0; r < 4; ++r) rowsum[mt][r] = 0.f;

  const float sc1 = 1.0f / 16384.0f;             // (1/M)/16
  const float sc2 = 1.0f / 16777216.0f;          // (1/M^2)/16

  for (int n0 = 0; n0 < 1024; n0 += 128) {
    // ---- S = kT(stripe) * kT(chunk)^T, K=256 ----
    f32x4 acc_s[4][2];
    #pragma unroll
    for (int mt = 0; mt < 4; ++mt)
      #pragma unroll
      for (int nt = 0; nt < 2; ++nt) acc_s[mt][nt] = zz;
    const short* Bn = kTb + (size_t)n0 * 256;
    for (int ks = 0; ks < 4; ++ks) {
      __syncthreads();
      #pragma unroll
      for (int j = 0; j < 4; ++j) {
        int s = w * 4 + j;
        gll16(Bn + (size_t)(s * 8 + srow) * 256 + ks * 64 + gcol, Bst + s * 1024);
      }
      __syncthreads();
      #pragma unroll
      for (int kq = 0; kq < 2; ++kq) {
        int sw = ((kq * 4 + q) ^ (i & 7)) * 16;
        bf8 af[4], bq2[2];
        #pragma unroll
        for (int mt = 0; mt < 4; ++mt)
          af[mt] = *(const bf8*)(Apan + ks * 8192 + (mt * 16 + i) * 128 + sw);
        #pragma unroll
        for (int nt = 0; nt < 2; ++nt)
          bq2[nt] = *(const bf8*)(Bst + (w * 32 + nt * 16 + i) * 128 + sw);
        #pragma unroll
        for (int mt = 0; mt < 4; ++mt)
          #pragma unroll
          for (int nt = 0; nt < 2; ++nt)
            acc_s[mt][nt] = MFMA16(af[mt], bq2[nt], acc_s[mt][nt]);
      }
    }
    // ---- exp -> P panels (A-operand layout), rowsum accumulate ----
    float sn0 = sB[n0 + w * 32 + i];
    float sn1 = sB[n0 + w * 32 + 16 + i];
    #pragma unroll
    for (int nt = 0; nt < 2; ++nt) {
      float sn = nt ? sn1 : sn0;
      int nl = w * 32 + nt * 16 + i;
      char* pbase = Ppan + (nl >> 6) * 8192 + (nl & 7) * 2;
      int gchunk = (nl >> 3) & 7;
      #pragma unroll
      for (int mt = 0; mt < 4; ++mt)
        #pragma unroll
        for (int r = 0; r < 4; ++r) {
          int ml = mt * 16 + q * 4 + r;
          float p = __expf(acc_s[mt][nt][r] * sc1 - sm[mt][r] * sn * sc2);
          rowsum[mt][r] += p;
          *(short*)(pbase + ml * 128 + ((gchunk ^ (ml & 7)) * 16)) = f2bf(p);
        }
    }
    // ---- O += P * vT(chunk)^T, K=128 (A=P from LDS, no staging) ----
    for (int ks2 = 0; ks2 < 2; ++ks2) {
      __syncthreads();                           // orders P writes (all waves) too
      #pragma unroll
      for (int j = 0; j < 8; ++j) {
        int s = w * 8 + j;
        gll16(vTb + (size_t)(s * 8 + srow) * 1024 + n0 + ks2 * 64 + gcol,
              Bst + s * 1024);
      }
      __syncthreads();
      #pragma unroll
      for (int kq = 0; kq < 2; ++kq) {
        int sw = ((kq * 4 + q) ^ (i & 7)) * 16;
        bf8 ap[4], bv4[4];
        #pragma unroll
        for (int mt = 0; mt < 4; ++mt)
          ap[mt] = *(const bf8*)(Ppan + ks2 * 8192 + (mt * 16 + i) * 128 + sw);
        #pragma unroll
        for (int ct = 0; ct < 4; ++ct)
          bv4[ct] = *(const bf8*)(Bst + (w * 64 + ct * 16 + i) * 128 + sw);
        #pragma unroll
        for (int mt = 0; mt < 4; ++mt)
          #pragma unroll
          for (int ct = 0; ct < 4; ++ct)
            acc_o[mt][ct] = MFMA16(ap[mt], bv4[ct], acc_o[mt][ct]);
      }
    }
  }
  // ---- softmax rowsums: wave-reduce over i, block-reduce over waves ----
  #pragma unroll
  for (int mask = 1; mask <= 8; mask <<= 1)
    #pragma unroll
    for (int mt = 0; mt < 4; ++mt)
      #pragma unroll
      for (int r = 0; r < 4; ++r) rowsum[mt][r] += __shfl_xor(rowsum[mt][r], mask, 64);
  __syncthreads();                               // all PV P-reads done; reuse Ppan
  float* rs = (float*)Ppan;                      // [4 waves][64 m]
  if (i == 0) {
    #pragma unroll
    for (int mt = 0; mt < 4; ++mt)
      #pragma unroll
      for (int r = 0; r < 4; ++r)
        rs[w * 64 + mt * 16 + q * 4 + r] = rowsum[mt][r];
  }
  __syncthreads();
  float rinv[4][4];
  #pragma unroll
  for (int mt = 0; mt < 4; ++mt)
    #pragma unroll
    for (int r = 0; r < 4; ++r) {
      int m = mt * 16 + q * 4 + r;
      rinv[mt][r] = 1.0f / (rs[m] + rs[64 + m] + rs[128 + m] + rs[192 + m]);
    }
  // ---- normalize + OB write via per-wave LDS restage (self-contained slot) ----
  short* ob = (short*)(Bst + w * 8192);          // 256 rows x 16 shorts
  #pragma unroll
  for (int mt = 0; mt < 4; ++mt)
    #pragma unroll
    for (int ct = 0; ct < 4; ++ct)
      #pragma unroll
      for (int r = 0; r < 4; ++r)
        ob[(r * 64 + ct * 16 + i) * 16 + mt * 4 + q] =
            f2bf(acc_o[mt][ct][r] * rinv[mt][r]);
  short* obg = OB + (size_t)b * 1024 * 256;
  #pragma unroll
  for (int jj = 0; jj < 8; ++jj) {
    int lr = jj * 32 + (l >> 1), ch = l & 1;
    bf8 vv = *(const bf8*)(ob + lr * 16 + ch * 8);
    int rr = lr >> 6, cc = lr & 63;
    *(bf8*)(obg + ((size_t)(rr * 256 + w * 64 + cc)) * 256 + bm * 16 + ch * 8) = vv;
  }
}

// ---------------- K3: output projection + bias + residual ----------------
__global__ __launch_bounds__(256, 2) void k3_out(const short* __restrict__ Wo_bf,
                                                 const short* __restrict__ OB,
                                                 const float* __restrict__ bo,
                                                 const float* __restrict__ x,
                                                 float* __restrict__ out) {
  __shared__ __attribute__((aligned(16))) char smem[32768];
  f32x4 acc[4][4];
  int bm = blockIdx.x, bn = blockIdx.y, b = blockIdx.z;
  gemm_core(Wo_bf + (size_t)bm * 128 * 256,
            OB + ((size_t)b * 1024 + bn * 128) * 256, 256, 256, 4, smem, acc);
  int tid = threadIdx.x;
  int w = tid >> 6, l = tid & 63, q = l >> 4, i = l & 15;
  int wm = w & 1, wn = w >> 1;
  int oloc = bm * 128 + wm * 64, sploc = bn * 128 + wn * 64;
  #pragma unroll
  for (int mt = 0; mt < 4; ++mt)
    #pragma unroll
    for (int r = 0; r < 4; ++r) {
      int o = oloc + mt * 16 + q * 4 + r;
      float bias = bo[o];
      #pragma unroll
      for (int nt = 0; nt < 4; ++nt) {
        int sp = sploc + nt * 16 + i;
        size_t idx = ((size_t)b * 512 + o) * 1024 + sp;
        out[idx] = acc[mt][nt][r] + bias + x[idx];
      }
    }
}

extern "C" void kernel_launch(void* const* d_in, const int* in_sizes, int n_in,
                              void* d_out, int out_size, void* d_ws, size_t ws_size,
                              hipStream_t stream) {
  (void)in_sizes; (void)n_in; (void)out_size; (void)ws_size;
  const float* x  = (const float*)d_in[0];
  const float* Wk = (const float*)d_in[1];
  const float* bk = (const float*)d_in[2];
  const float* Wv = (const float*)d_in[3];
  const float* bv = (const float*)d_in[4];
  const float* Wo = (const float*)d_in[5];
  const float* bo = (const float*)d_in[6];
  float* out = (float*)d_out;
  char* ws = (char*)d_ws;

  // ws layout (~68.5 MB), time-aliased:
  //   [0,32M)   : xT (P0->K1, 32 MB) then OB (K2->K3, 16 MB)
  //   [32M,48M) : kT (K1->K2)
  //   [48M,64M) : vT (K1->K2)
  //   [64M,...) : weights + reduction buffers
  short* xT     = (short*)(ws);
  short* OB     = (short*)(ws);
  short* kTb    = (short*)(ws + 33554432);
  short* vTb    = (short*)(ws + 50331648);
  short* Wkv_bf = (short*)(ws + 67108864);
  short* Wo_bf  = (short*)(ws + 67633152);
  float* s_part = (float*)(ws + 67895296);
  float* s_buf  = (float*)(ws + 68419584);

  p0_xpose<<<dim3(8, 16, 32), 256, 0, stream>>>(x, xT);
  w0_weights<<<1536, 256, 0, stream>>>(Wk, Wv, Wo, Wkv_bf, Wo_bf);
  k1_kv<<<dim3(256, 4), 256, 0, stream>>>(xT, Wkv_bf, bk, bv, kTb, vTb, s_part);
  k1b_sum<<<128, 256, 0, stream>>>(s_part, s_buf);
  k2_fused<<<dim3(16, 32), 256, 0, stream>>>(kTb, vTb, s_buf, OB);
  k3_out<<<dim3(4, 8, 32), 256, 0, stream>>>(Wo_bf, OB, bo, x, out);
}